// Round 4
// baseline (552.361 us; speedup 1.0000x reference)
//
#include <hip/hip_runtime.h>

#define BN 2048   // batch
#define TN 2048   // time
#define BATCH 8   // steps per register-batched load group
#define SLOT 24   // floats per (b,chunk) slot: 16 P + 4 off + 1 gold + 3 pad

__device__ __forceinline__ float ex2(float x){ return __builtin_amdgcn_exp2f(x); }
__device__ __forceinline__ float lg2(float x){ return __builtin_amdgcn_logf(x); }
__device__ __forceinline__ float rcpf(float x){ return __builtin_amdgcn_rcpf(x); }

constexpr float kLog2e = 1.4426950408889634f;
constexpr float kLn2   = 0.6931471805599453f;

__device__ __forceinline__ float fast_tanh(float x){
    float ax = fabsf(x);
    float e  = ex2(ax * (-2.0f * kLog2e));     // exp(-2|x|)
    float t  = (1.0f - e) * rcpf(1.0f + e);
    return copysignf(t, x);
}

__device__ __forceinline__ float sel4(float v0, float v1, float v2, float v3, int idx){
    float r = (idx == 1) ? v1 : v0;
    r = (idx == 2) ? v2 : r;
    r = (idx == 3) ? v3 : r;
    return r;
}

// Evolve NCOL exp-space alpha columns through one chunk (TCH steps) with
// register-batched global loads. Only the 4 live states of feats are loaded
// (2x float2 per step) to keep the register peak low.
template <int NCOL, bool CHUNK0, int TCH>
__device__ __forceinline__ void run_chunk(
    int b, int c,
    const float* __restrict__ feats, const float* __restrict__ bias,
    const int* __restrict__ tags,
    const float (&AL)[4][4], const float (&M)[4][4],
    const float (&wsv)[4], const float (&wwv)[4], const float (&wnv)[4],
    float bwc, float bnc, const float* sA, const float* sM,
    const float (&tc4)[4],
    float (&P)[4][NCOL], float (&lacc)[NCOL], float& gold, int& prev)
{
    const int t0c = c * TCH;
    #pragma unroll 1
    for (int bt = 0; bt < TCH / BATCH; ++bt) {
        const int t0 = t0c + bt * BATCH;
        // ---- batched loads ----
        float Fr[BATCH * 4];
        {
            const float* fb = feats + ((size_t)b * TN + t0) * 6;
            #pragma unroll
            for (int s2 = 0; s2 < BATCH; ++s2) {
                const float2 u = *(const float2*)(fb + s2 * 6);
                const float2 v = *(const float2*)(fb + s2 * 6 + 2);
                Fr[s2*4+0] = u.x; Fr[s2*4+1] = u.y;
                Fr[s2*4+2] = v.x; Fr[s2*4+3] = v.y;
            }
        }
        float Bv[BATCH];
        {
            const float4* bp4 = (const float4*)(bias + (size_t)b * TN + t0);
            #pragma unroll
            for (int q = 0; q < BATCH / 4; ++q) {
                const float4 v = bp4[q];
                Bv[q*4+0] = v.x; Bv[q*4+1] = v.y; Bv[q*4+2] = v.z; Bv[q*4+3] = v.w;
            }
        }
        int Tg[BATCH];
        {
            const int4* tp4 = (const int4*)(tags + (size_t)b * TN + t0);
            #pragma unroll
            for (int q = 0; q < BATCH / 4; ++q) {
                const int4 v = tp4[q];
                Tg[q*4+0] = v.x; Tg[q*4+1] = v.y; Tg[q*4+2] = v.z; Tg[q*4+3] = v.w;
            }
        }
        // ---- compute BATCH steps ----
        #pragma unroll
        for (int s = 0; s < BATCH; ++s) {
            const float fi0 = Fr[s*4+0], fi1 = Fr[s*4+1];
            const float fi2 = Fr[s*4+2], fi3 = Fr[s*4+3];
            if (CHUNK0 && bt == 0 && s == 0) {
                // closed-form t=0: alpha1[i] = f[0,i] + trans[i,START]
                const float a0 = fi0 + tc4[0], a1 = fi1 + tc4[1];
                const float a2 = fi2 + tc4[2], a3 = fi3 + tc4[3];
                const float mx = fmaxf(fmaxf(a0, a1), fmaxf(a2, a3));
                P[0][0] = ex2((a0 - mx) * kLog2e);
                P[1][0] = ex2((a1 - mx) * kLog2e);
                P[2][0] = ex2((a2 - mx) * kLog2e);
                P[3][0] = ex2((a3 - mx) * kLog2e);
                lacc[0] = mx * kLog2e;
                const int tg0 = Tg[0];
                gold = sel4(tc4[0], tc4[1], tc4[2], tc4[3], tg0)
                     + sel4(fi0, fi1, fi2, fi3, tg0);
                prev = tg0;
                continue;
            }
            const float bv = Bv[s];
            const int tg = Tg[s];
            const bool hw = bv > 0.5f;
            const float bc = hw ? bwc : bnc;
            float g[4], gL[4];
            #pragma unroll
            for (int j = 0; j < 4; ++j) {
                float x = fmaf(bv, wsv[j], bc);
                g[j]  = (hw ? wwv[j] : wnv[j]) * fast_tanh(x);
                gL[j] = g[j] * kLog2e;
            }
            const float fiL[4] = { fi0 * kLog2e, fi1 * kLog2e,
                                   fi2 * kLog2e, fi3 * kLog2e };
            float nP[4][NCOL];
            #pragma unroll
            for (int i = 0; i < 4; ++i)
                #pragma unroll
                for (int j = 0; j < NCOL; ++j) nP[i][j] = 0.0f;
            #pragma unroll
            for (int k = 0; k < 4; ++k) {
                float Ek[4];
                #pragma unroll
                for (int i = 0; i < 4; ++i)
                    Ek[i] = ex2(fmaf(gL[k], M[i][k], fiL[i] + AL[i][k]));
                #pragma unroll
                for (int j = 0; j < NCOL; ++j) {
                    const float pk = P[k][j];
                    #pragma unroll
                    for (int i = 0; i < 4; ++i) nP[i][j] = fmaf(Ek[i], pk, nP[i][j]);
                }
            }
            #pragma unroll
            for (int i = 0; i < 4; ++i)
                #pragma unroll
                for (int j = 0; j < NCOL; ++j) P[i][j] = nP[i][j];

            const int idx = tg * 4 + prev;
            gold += sA[idx] + sel4(g[0], g[1], g[2], g[3], prev) * sM[idx]
                  + sel4(fi0, fi1, fi2, fi3, tg);
            prev = tg;

            if ((s & 3) == 3) {     // exact pow2 renorm every 4 steps
                #pragma unroll
                for (int j = 0; j < NCOL; ++j) {
                    float m = fmaxf(fmaxf(P[0][j], P[1][j]), fmaxf(P[2][j], P[3][j]));
                    int ee = (int)((__float_as_uint(m) >> 23) & 255u) - 126;
                    float sc = __uint_as_float((unsigned)(127 - ee) << 23);
                    lacc[j] += (float)ee;
                    #pragma unroll
                    for (int i = 0; i < 4; ++i) P[i][j] *= sc;
                }
            }
        }
    }
}

template <int CCv>
__global__ void __launch_bounds__(256, 5)   // cap VGPR at ~102 -> >=20 waves/CU
crf_phase1(const float* __restrict__ feats, const float* __restrict__ bias,
           const int* __restrict__ tags, const float* __restrict__ trans,
           const float* __restrict__ wsh, const float* __restrict__ bno,
           const float* __restrict__ bwi, const float* __restrict__ wwo,
           const float* __restrict__ wno, const float* __restrict__ mult,
           float* __restrict__ matAll)
{
    constexpr int TCHv = TN / CCv;
    const int tid = blockIdx.x * 256 + threadIdx.x;
    const int b = tid & (BN - 1);
    const int c = tid >> 11;        // uniform per block

    __shared__ float sA[16], sM[16];
    if (threadIdx.x < 16) {
        const int i = threadIdx.x >> 2, j = threadIdx.x & 3;
        sA[threadIdx.x] = trans[i * 6 + j];
        const float m0 = mult[j], m1 = mult[4 + j], m2 = mult[8 + j], m3 = mult[12 + j];
        const float mx = fmaxf(fmaxf(m0, m1), fmaxf(m2, m3));
        const float e0 = ex2((m0 - mx) * kLog2e), e1 = ex2((m1 - mx) * kLog2e);
        const float e2 = ex2((m2 - mx) * kLog2e), e3 = ex2((m3 - mx) * kLog2e);
        const float inv = rcpf(e0 + e1 + e2 + e3);
        const float ei = (i == 0) ? e0 : (i == 1) ? e1 : (i == 2) ? e2 : e3;
        sM[threadIdx.x] = (i == j) ? -1.0f : ei * inv;
    }
    __syncthreads();

    float AL[4][4], M[4][4];
    #pragma unroll
    for (int i = 0; i < 4; ++i)
        #pragma unroll
        for (int j = 0; j < 4; ++j) {
            AL[i][j] = trans[i * 6 + j] * kLog2e;
            M[i][j]  = sM[i * 4 + j];
        }
    float wsv[4], wwv[4], wnv[4];
    #pragma unroll
    for (int j = 0; j < 4; ++j) { wsv[j] = wsh[j]; wwv[j] = wwo[j]; wnv[j] = wno[j]; }
    const float bwc = bwi[0], bnc = bno[0];
    const float tc4[4] = { trans[4], trans[10], trans[16], trans[22] };

    float o[SLOT];
    float gold = 0.0f;
    int prev;
    if (c == 0) {
        float P[4][1], lacc[1];
        run_chunk<1, true, TCHv>(b, 0, feats, bias, tags, AL, M, wsv, wwv, wnv,
                                 bwc, bnc, sA, sM, tc4, P, lacc, gold, prev);
        #pragma unroll
        for (int i = 0; i < 4; ++i)
            #pragma unroll
            for (int j = 0; j < 4; ++j) o[i * 4 + j] = P[i][0];   // rank-1 lift
        #pragma unroll
        for (int j = 0; j < 4; ++j) o[16 + j] = lacc[0];
    } else {
        float P[4][4], lacc[4] = {0.f, 0.f, 0.f, 0.f};
        #pragma unroll
        for (int i = 0; i < 4; ++i)
            #pragma unroll
            for (int j = 0; j < 4; ++j) P[i][j] = (i == j) ? 1.0f : 0.0f;
        prev = tags[(size_t)b * TN + c * TCHv - 1];
        run_chunk<4, false, TCHv>(b, c, feats, bias, tags, AL, M, wsv, wwv, wnv,
                                  bwc, bnc, sA, sM, tc4, P, lacc, gold, prev);
        #pragma unroll
        for (int i = 0; i < 4; ++i)
            #pragma unroll
            for (int j = 0; j < 4; ++j) o[i * 4 + j] = P[i][j];
        #pragma unroll
        for (int j = 0; j < 4; ++j) o[16 + j] = lacc[j];
    }
    o[20] = gold; o[21] = 0.f; o[22] = 0.f; o[23] = 0.f;
    float4* s4 = (float4*)(matAll + ((size_t)b * CCv + c) * SLOT);
    #pragma unroll
    for (int q = 0; q < SLOT / 4; ++q)
        s4[q] = make_float4(o[4*q], o[4*q+1], o[4*q+2], o[4*q+3]);
}

// C = A∘B (A later, B earlier) in exp-space with per-column base-2 offsets.
__device__ __forceinline__ void compose4(
    const float (&Ae)[4][4], const float (&sa)[4],
    const float (&Be)[4][4], const float (&sb)[4],
    float (&Ce)[4][4], float (&sc)[4])
{
    const float maxA = fmaxf(fmaxf(sa[0], sa[1]), fmaxf(sa[2], sa[3]));
    float Ap[4][4];
    #pragma unroll
    for (int k = 0; k < 4; ++k) {
        const float wk = ex2(sa[k] - maxA);
        #pragma unroll
        for (int i = 0; i < 4; ++i) Ap[i][k] = Ae[i][k] * wk;
    }
    #pragma unroll
    for (int j = 0; j < 4; ++j) {
        float c0 = 0.f, c1 = 0.f, c2 = 0.f, c3 = 0.f;
        #pragma unroll
        for (int k = 0; k < 4; ++k) {
            const float bk = Be[k][j];
            c0 = fmaf(Ap[0][k], bk, c0);
            c1 = fmaf(Ap[1][k], bk, c1);
            c2 = fmaf(Ap[2][k], bk, c2);
            c3 = fmaf(Ap[3][k], bk, c3);
        }
        const float m = fmaxf(fmaxf(c0, c1), fmaxf(c2, c3));
        const int ee = (int)((__float_as_uint(m) >> 23) & 255u) - 126;
        const float scf = __uint_as_float((unsigned)(127 - ee) << 23);
        Ce[0][j] = c0 * scf; Ce[1][j] = c1 * scf;
        Ce[2][j] = c2 * scf; Ce[3][j] = c3 * scf;
        sc[j] = sb[j] + maxA + (float)ee;
    }
}

template <int CCv>
__global__ void __launch_bounds__(256)
crf_phase2(const float* __restrict__ matAll, const float* __restrict__ trans,
           const int* __restrict__ tags, float* __restrict__ out)
{
    constexpr int CPL = CCv / 64;   // chunks per lane
    const int gtid = blockIdx.x * 256 + threadIdx.x;
    const int b = gtid >> 6;
    const int lane = threadIdx.x & 63;

    const float4* base = (const float4*)(matAll + ((size_t)b * CCv + lane * CPL) * SLOT);
    float Pe[4][4], so[4], gold;
    {
        float A[SLOT];
        #pragma unroll
        for (int q = 0; q < SLOT / 4; ++q) {
            const float4 v = base[q];
            A[4*q] = v.x; A[4*q+1] = v.y; A[4*q+2] = v.z; A[4*q+3] = v.w;
        }
        #pragma unroll
        for (int i = 0; i < 4; ++i)
            #pragma unroll
            for (int j = 0; j < 4; ++j) Pe[i][j] = A[i * 4 + j];
        #pragma unroll
        for (int j = 0; j < 4; ++j) so[j] = A[16 + j];
        gold = A[20];
    }
    #pragma unroll
    for (int q = 1; q < CPL; ++q) {
        float A[SLOT];
        #pragma unroll
        for (int r = 0; r < SLOT / 4; ++r) {
            const float4 v = base[q * (SLOT / 4) + r];
            A[4*r] = v.x; A[4*r+1] = v.y; A[4*r+2] = v.z; A[4*r+3] = v.w;
        }
        float Ae[4][4], sa[4];
        #pragma unroll
        for (int i = 0; i < 4; ++i)
            #pragma unroll
            for (int j = 0; j < 4; ++j) Ae[i][j] = A[i * 4 + j];
        #pragma unroll
        for (int j = 0; j < 4; ++j) sa[j] = A[16 + j];
        gold += A[20];
        float Ce[4][4], sc[4];
        compose4(Ae, sa, Pe, so, Ce, sc);     // newer slot is the later operator
        #pragma unroll
        for (int i = 0; i < 4; ++i)
            #pragma unroll
            for (int j = 0; j < 4; ++j) Pe[i][j] = Ce[i][j];
        #pragma unroll
        for (int j = 0; j < 4; ++j) so[j] = sc[j];
    }

    #pragma unroll
    for (int d = 1; d < 64; d <<= 1) {
        float oP[4][4], os[4];
        #pragma unroll
        for (int i = 0; i < 4; ++i)
            #pragma unroll
            for (int j = 0; j < 4; ++j) oP[i][j] = __shfl_xor(Pe[i][j], d, 64);
        #pragma unroll
        for (int j = 0; j < 4; ++j) os[j] = __shfl_xor(so[j], d, 64);
        const bool hi = (lane & d) != 0;
        float Ae[4][4], Be[4][4], sa[4], sb[4];
        #pragma unroll
        for (int i = 0; i < 4; ++i)
            #pragma unroll
            for (int j = 0; j < 4; ++j) {
                Ae[i][j] = hi ? Pe[i][j] : oP[i][j];
                Be[i][j] = hi ? oP[i][j] : Pe[i][j];
            }
        #pragma unroll
        for (int j = 0; j < 4; ++j) {
            sa[j] = hi ? so[j] : os[j];
            sb[j] = hi ? os[j] : so[j];
        }
        float Ce[4][4], sc[4];
        compose4(Ae, sa, Be, sb, Ce, sc);
        #pragma unroll
        for (int i = 0; i < 4; ++i)
            #pragma unroll
            for (int j = 0; j < 4; ++j) Pe[i][j] = Ce[i][j];
        #pragma unroll
        for (int j = 0; j < 4; ++j) so[j] = sc[j];
    }

    #pragma unroll
    for (int d = 1; d < 64; d <<= 1) gold += __shfl_xor(gold, d, 64);

    if (lane == 0) {
        const float t50 = trans[30], t51 = trans[31], t52 = trans[32], t53 = trans[33];
        const float ssum = Pe[0][0] * ex2(t50 * kLog2e) + Pe[1][0] * ex2(t51 * kLog2e)
                         + Pe[2][0] * ex2(t52 * kLog2e) + Pe[3][0] * ex2(t53 * kLog2e);
        const float fwd = (so[0] + lg2(ssum)) * kLn2;
        const int lastT = tags[(size_t)b * TN + TN - 1];
        const float gfin = gold + sel4(t50, t51, t52, t53, lastT);
        out[b] = fwd - gfin;
    }
}

extern "C" void kernel_launch(void* const* d_in, const int* in_sizes, int n_in,
                              void* d_out, int out_size, void* d_ws, size_t ws_size,
                              hipStream_t stream)
{
    const float* feats = (const float*)d_in[0];
    const float* bias  = (const float*)d_in[1];
    const int*   tags  = (const int*)d_in[2];
    const float* trans = (const float*)d_in[3];
    const float* wsh   = (const float*)d_in[4];
    const float* bno   = (const float*)d_in[5];
    const float* bwi   = (const float*)d_in[6];
    const float* wwo   = (const float*)d_in[7];
    const float* wno   = (const float*)d_in[8];
    const float* mult  = (const float*)d_in[9];
    float* out = (float*)d_out;
    float* matAll = (float*)d_ws;

    const size_t need256 = (size_t)BN * 256 * SLOT * sizeof(float);  // 50.3 MB
    const size_t need128 = (size_t)BN * 128 * SLOT * sizeof(float);  // 25.2 MB
    if (ws_size >= need256) {
        crf_phase1<256><<<(256 * BN) / 256, 256, 0, stream>>>(
            feats, bias, tags, trans, wsh, bno, bwi, wwo, wno, mult, matAll);
        crf_phase2<256><<<(BN * 64) / 256, 256, 0, stream>>>(matAll, trans, tags, out);
    } else if (ws_size >= need128) {
        crf_phase1<128><<<(128 * BN) / 256, 256, 0, stream>>>(
            feats, bias, tags, trans, wsh, bno, bwi, wwo, wno, mult, matAll);
        crf_phase2<128><<<(BN * 64) / 256, 256, 0, stream>>>(matAll, trans, tags, out);
    } else {
        crf_phase1<64><<<(64 * BN) / 256, 256, 0, stream>>>(
            feats, bias, tags, trans, wsh, bno, bwi, wwo, wno, mult, matAll);
        crf_phase2<64><<<(BN * 64) / 256, 256, 0, stream>>>(matAll, trans, tags, out);
    }
}

// Round 5
// 233.043 us; speedup vs baseline: 2.3702x; 2.3702x over previous
//
#include <hip/hip_runtime.h>

#define BN 2048   // batch
#define TN 2048   // time
#define BATCH 8   // steps per register-batched load group
#define SLOT 24   // floats per (b,chunk) slot: 16 P + 4 off + 1 gold + 3 pad

__device__ __forceinline__ float ex2(float x){ return __builtin_amdgcn_exp2f(x); }
__device__ __forceinline__ float lg2(float x){ return __builtin_amdgcn_logf(x); }
__device__ __forceinline__ float rcpf(float x){ return __builtin_amdgcn_rcpf(x); }
__device__ __forceinline__ float rfl(float x){
    return __int_as_float(__builtin_amdgcn_readfirstlane(__float_as_int(x)));
}

constexpr float kLog2e = 1.4426950408889634f;
constexpr float kLn2   = 0.6931471805599453f;

__device__ __forceinline__ float fast_tanh(float x){
    float ax = fabsf(x);
    float e  = ex2(ax * (-2.0f * kLog2e));     // exp(-2|x|)
    float t  = (1.0f - e) * rcpf(1.0f + e);
    return copysignf(t, x);
}

__device__ __forceinline__ float sel4(float v0, float v1, float v2, float v3, int idx){
    float r = (idx == 1) ? v1 : v0;
    r = (idx == 2) ? v2 : r;
    r = (idx == 3) ? v3 : r;
    return r;
}

// Evolve NCOL exp-space alpha columns through one chunk (TCH steps).
// Feats: only the 4 live states are loaded (2x float2 per step) -> 32 regs.
template <int NCOL, bool CHUNK0, int TCH>
__device__ __forceinline__ void run_chunk(
    int b, int c,
    const float* __restrict__ feats, const float* __restrict__ bias,
    const int* __restrict__ tags,
    const float (&AL)[4][4], const float (&M)[4][4],
    const float (&wsv)[4], const float (&wwv)[4], const float (&wnv)[4],
    float bwc, float bnc, const float* sA, const float* sM,
    const float (&tc4)[4],
    float (&P)[4][NCOL], float (&lacc)[NCOL], float& gold, int& prev)
{
    const int t0c = c * TCH;
    #pragma unroll 1
    for (int bt = 0; bt < TCH / BATCH; ++bt) {
        const int t0 = t0c + bt * BATCH;
        // ---- batched loads ----
        float Fr[BATCH * 4];
        {
            const float* fb = feats + ((size_t)b * TN + t0) * 6;
            #pragma unroll
            for (int s2 = 0; s2 < BATCH; ++s2) {
                const float2 u = *(const float2*)(fb + s2 * 6);
                const float2 v = *(const float2*)(fb + s2 * 6 + 2);
                Fr[s2*4+0] = u.x; Fr[s2*4+1] = u.y;
                Fr[s2*4+2] = v.x; Fr[s2*4+3] = v.y;
            }
        }
        float Bv[BATCH];
        {
            const float4* bp4 = (const float4*)(bias + (size_t)b * TN + t0);
            #pragma unroll
            for (int q = 0; q < BATCH / 4; ++q) {
                const float4 v = bp4[q];
                Bv[q*4+0] = v.x; Bv[q*4+1] = v.y; Bv[q*4+2] = v.z; Bv[q*4+3] = v.w;
            }
        }
        int Tg[BATCH];
        {
            const int4* tp4 = (const int4*)(tags + (size_t)b * TN + t0);
            #pragma unroll
            for (int q = 0; q < BATCH / 4; ++q) {
                const int4 v = tp4[q];
                Tg[q*4+0] = v.x; Tg[q*4+1] = v.y; Tg[q*4+2] = v.z; Tg[q*4+3] = v.w;
            }
        }
        // ---- compute BATCH steps ----
        #pragma unroll
        for (int s = 0; s < BATCH; ++s) {
            const float fi0 = Fr[s*4+0], fi1 = Fr[s*4+1];
            const float fi2 = Fr[s*4+2], fi3 = Fr[s*4+3];
            if (CHUNK0 && bt == 0 && s == 0) {
                // closed-form t=0: alpha1[i] = f[0,i] + trans[i,START]
                const float a0 = fi0 + tc4[0], a1 = fi1 + tc4[1];
                const float a2 = fi2 + tc4[2], a3 = fi3 + tc4[3];
                const float mx = fmaxf(fmaxf(a0, a1), fmaxf(a2, a3));
                P[0][0] = ex2((a0 - mx) * kLog2e);
                P[1][0] = ex2((a1 - mx) * kLog2e);
                P[2][0] = ex2((a2 - mx) * kLog2e);
                P[3][0] = ex2((a3 - mx) * kLog2e);
                lacc[0] = mx * kLog2e;
                const int tg0 = Tg[0];
                gold = sel4(tc4[0], tc4[1], tc4[2], tc4[3], tg0)
                     + sel4(fi0, fi1, fi2, fi3, tg0);
                prev = tg0;
                continue;
            }
            const float bv = Bv[s];
            const int tg = Tg[s];
            const bool hw = bv > 0.5f;
            const float bc = hw ? bwc : bnc;
            float g[4], gL[4];
            #pragma unroll
            for (int j = 0; j < 4; ++j) {
                float x = fmaf(bv, wsv[j], bc);
                g[j]  = (hw ? wwv[j] : wnv[j]) * fast_tanh(x);
                gL[j] = g[j] * kLog2e;
            }
            const float fiL[4] = { fi0 * kLog2e, fi1 * kLog2e,
                                   fi2 * kLog2e, fi3 * kLog2e };
            float nP[4][NCOL];
            #pragma unroll
            for (int i = 0; i < 4; ++i)
                #pragma unroll
                for (int j = 0; j < NCOL; ++j) nP[i][j] = 0.0f;
            #pragma unroll
            for (int k = 0; k < 4; ++k) {
                float Ek[4];
                #pragma unroll
                for (int i = 0; i < 4; ++i)
                    Ek[i] = ex2(fmaf(gL[k], M[i][k], fiL[i] + AL[i][k]));
                #pragma unroll
                for (int j = 0; j < NCOL; ++j) {
                    const float pk = P[k][j];
                    #pragma unroll
                    for (int i = 0; i < 4; ++i) nP[i][j] = fmaf(Ek[i], pk, nP[i][j]);
                }
            }
            #pragma unroll
            for (int i = 0; i < 4; ++i)
                #pragma unroll
                for (int j = 0; j < NCOL; ++j) P[i][j] = nP[i][j];

            const int idx = tg * 4 + prev;
            gold += sA[idx] + sel4(g[0], g[1], g[2], g[3], prev) * sM[idx]
                  + sel4(fi0, fi1, fi2, fi3, tg);
            prev = tg;

            if ((s & 3) == 3) {     // exact pow2 renorm every 4 steps
                #pragma unroll
                for (int j = 0; j < NCOL; ++j) {
                    float m = fmaxf(fmaxf(P[0][j], P[1][j]), fmaxf(P[2][j], P[3][j]));
                    int ee = (int)((__float_as_uint(m) >> 23) & 255u) - 126;
                    float sc = __uint_as_float((unsigned)(127 - ee) << 23);
                    lacc[j] += (float)ee;
                    #pragma unroll
                    for (int i = 0; i < 4; ++i) P[i][j] *= sc;
                }
            }
        }
    }
}

template <int CCv>
__global__ void __launch_bounds__(256)
crf_phase1(const float* __restrict__ feats, const float* __restrict__ bias,
           const int* __restrict__ tags, const float* __restrict__ trans,
           const float* __restrict__ wsh, const float* __restrict__ bno,
           const float* __restrict__ bwi, const float* __restrict__ wwo,
           const float* __restrict__ wno, const float* __restrict__ mult,
           float* __restrict__ matAll)
{
    constexpr int TCHv = TN / CCv;
    const int tid = blockIdx.x * 256 + threadIdx.x;
    const int b = tid & (BN - 1);
    const int c = tid >> 11;        // uniform per block

    __shared__ float sA[16], sM[16];
    if (threadIdx.x < 16) {
        const int i = threadIdx.x >> 2, j = threadIdx.x & 3;
        sA[threadIdx.x] = trans[i * 6 + j];
        const float m0 = mult[j], m1 = mult[4 + j], m2 = mult[8 + j], m3 = mult[12 + j];
        const float mx = fmaxf(fmaxf(m0, m1), fmaxf(m2, m3));
        const float e0 = ex2((m0 - mx) * kLog2e), e1 = ex2((m1 - mx) * kLog2e);
        const float e2 = ex2((m2 - mx) * kLog2e), e3 = ex2((m3 - mx) * kLog2e);
        const float inv = rcpf(e0 + e1 + e2 + e3);
        const float ei = (i == 0) ? e0 : (i == 1) ? e1 : (i == 2) ? e2 : e3;
        sM[threadIdx.x] = (i == j) ? -1.0f : ei * inv;
    }
    __syncthreads();

    // Model params: AL comes from uniform global loads (compiler scalarizes);
    // M is recomputed per-lane and pinned into SGPRs via readfirstlane so the
    // 16 values don't occupy VGPRs across the whole hot loop.
    float AL[4][4], M[4][4];
    #pragma unroll
    for (int j = 0; j < 4; ++j) {
        const float m0 = mult[j], m1 = mult[4 + j], m2 = mult[8 + j], m3 = mult[12 + j];
        const float mx = fmaxf(fmaxf(m0, m1), fmaxf(m2, m3));
        const float e0 = ex2((m0 - mx) * kLog2e), e1 = ex2((m1 - mx) * kLog2e);
        const float e2 = ex2((m2 - mx) * kLog2e), e3 = ex2((m3 - mx) * kLog2e);
        const float inv = rcpf(e0 + e1 + e2 + e3);
        M[0][j] = (0 == j) ? -1.0f : rfl(e0 * inv);
        M[1][j] = (1 == j) ? -1.0f : rfl(e1 * inv);
        M[2][j] = (2 == j) ? -1.0f : rfl(e2 * inv);
        M[3][j] = (3 == j) ? -1.0f : rfl(e3 * inv);
    }
    #pragma unroll
    for (int i = 0; i < 4; ++i)
        #pragma unroll
        for (int j = 0; j < 4; ++j)
            AL[i][j] = trans[i * 6 + j] * kLog2e;
    float wsv[4], wwv[4], wnv[4];
    #pragma unroll
    for (int j = 0; j < 4; ++j) { wsv[j] = wsh[j]; wwv[j] = wwo[j]; wnv[j] = wno[j]; }
    const float bwc = bwi[0], bnc = bno[0];
    const float tc4[4] = { trans[4], trans[10], trans[16], trans[22] };

    float o[SLOT];
    float gold = 0.0f;
    int prev;
    if (c == 0) {
        float P[4][1], lacc[1];
        run_chunk<1, true, TCHv>(b, 0, feats, bias, tags, AL, M, wsv, wwv, wnv,
                                 bwc, bnc, sA, sM, tc4, P, lacc, gold, prev);
        #pragma unroll
        for (int i = 0; i < 4; ++i)
            #pragma unroll
            for (int j = 0; j < 4; ++j) o[i * 4 + j] = P[i][0];   // rank-1 lift
        #pragma unroll
        for (int j = 0; j < 4; ++j) o[16 + j] = lacc[0];
    } else {
        float P[4][4], lacc[4] = {0.f, 0.f, 0.f, 0.f};
        #pragma unroll
        for (int i = 0; i < 4; ++i)
            #pragma unroll
            for (int j = 0; j < 4; ++j) P[i][j] = (i == j) ? 1.0f : 0.0f;
        prev = tags[(size_t)b * TN + c * TCHv - 1];
        run_chunk<4, false, TCHv>(b, c, feats, bias, tags, AL, M, wsv, wwv, wnv,
                                  bwc, bnc, sA, sM, tc4, P, lacc, gold, prev);
        #pragma unroll
        for (int i = 0; i < 4; ++i)
            #pragma unroll
            for (int j = 0; j < 4; ++j) o[i * 4 + j] = P[i][j];
        #pragma unroll
        for (int j = 0; j < 4; ++j) o[16 + j] = lacc[j];
    }
    o[20] = gold; o[21] = 0.f; o[22] = 0.f; o[23] = 0.f;
    float4* s4 = (float4*)(matAll + ((size_t)b * CCv + c) * SLOT);
    #pragma unroll
    for (int q = 0; q < SLOT / 4; ++q)
        s4[q] = make_float4(o[4*q], o[4*q+1], o[4*q+2], o[4*q+3]);
}

// C = A∘B (A later, B earlier) in exp-space with per-column base-2 offsets.
__device__ __forceinline__ void compose4(
    const float (&Ae)[4][4], const float (&sa)[4],
    const float (&Be)[4][4], const float (&sb)[4],
    float (&Ce)[4][4], float (&sc)[4])
{
    const float maxA = fmaxf(fmaxf(sa[0], sa[1]), fmaxf(sa[2], sa[3]));
    float Ap[4][4];
    #pragma unroll
    for (int k = 0; k < 4; ++k) {
        const float wk = ex2(sa[k] - maxA);
        #pragma unroll
        for (int i = 0; i < 4; ++i) Ap[i][k] = Ae[i][k] * wk;
    }
    #pragma unroll
    for (int j = 0; j < 4; ++j) {
        float c0 = 0.f, c1 = 0.f, c2 = 0.f, c3 = 0.f;
        #pragma unroll
        for (int k = 0; k < 4; ++k) {
            const float bk = Be[k][j];
            c0 = fmaf(Ap[0][k], bk, c0);
            c1 = fmaf(Ap[1][k], bk, c1);
            c2 = fmaf(Ap[2][k], bk, c2);
            c3 = fmaf(Ap[3][k], bk, c3);
        }
        const float m = fmaxf(fmaxf(c0, c1), fmaxf(c2, c3));
        const int ee = (int)((__float_as_uint(m) >> 23) & 255u) - 126;
        const float scf = __uint_as_float((unsigned)(127 - ee) << 23);
        Ce[0][j] = c0 * scf; Ce[1][j] = c1 * scf;
        Ce[2][j] = c2 * scf; Ce[3][j] = c3 * scf;
        sc[j] = sb[j] + maxA + (float)ee;
    }
}

template <int CCv>
__global__ void __launch_bounds__(256)
crf_phase2(const float* __restrict__ matAll, const float* __restrict__ trans,
           const int* __restrict__ tags, float* __restrict__ out)
{
    constexpr int CPL = CCv / 64;   // chunks per lane
    const int gtid = blockIdx.x * 256 + threadIdx.x;
    const int b = gtid >> 6;
    const int lane = threadIdx.x & 63;

    const float4* base = (const float4*)(matAll + ((size_t)b * CCv + lane * CPL) * SLOT);
    float Pe[4][4], so[4], gold;
    {
        float A[SLOT];
        #pragma unroll
        for (int q = 0; q < SLOT / 4; ++q) {
            const float4 v = base[q];
            A[4*q] = v.x; A[4*q+1] = v.y; A[4*q+2] = v.z; A[4*q+3] = v.w;
        }
        #pragma unroll
        for (int i = 0; i < 4; ++i)
            #pragma unroll
            for (int j = 0; j < 4; ++j) Pe[i][j] = A[i * 4 + j];
        #pragma unroll
        for (int j = 0; j < 4; ++j) so[j] = A[16 + j];
        gold = A[20];
    }
    #pragma unroll
    for (int q = 1; q < CPL; ++q) {
        float A[SLOT];
        #pragma unroll
        for (int r = 0; r < SLOT / 4; ++r) {
            const float4 v = base[q * (SLOT / 4) + r];
            A[4*r] = v.x; A[4*r+1] = v.y; A[4*r+2] = v.z; A[4*r+3] = v.w;
        }
        float Ae[4][4], sa[4];
        #pragma unroll
        for (int i = 0; i < 4; ++i)
            #pragma unroll
            for (int j = 0; j < 4; ++j) Ae[i][j] = A[i * 4 + j];
        #pragma unroll
        for (int j = 0; j < 4; ++j) sa[j] = A[16 + j];
        gold += A[20];
        float Ce[4][4], sc[4];
        compose4(Ae, sa, Pe, so, Ce, sc);     // newer slot is the later operator
        #pragma unroll
        for (int i = 0; i < 4; ++i)
            #pragma unroll
            for (int j = 0; j < 4; ++j) Pe[i][j] = Ce[i][j];
        #pragma unroll
        for (int j = 0; j < 4; ++j) so[j] = sc[j];
    }

    #pragma unroll
    for (int d = 1; d < 64; d <<= 1) {
        float oP[4][4], os[4];
        #pragma unroll
        for (int i = 0; i < 4; ++i)
            #pragma unroll
            for (int j = 0; j < 4; ++j) oP[i][j] = __shfl_xor(Pe[i][j], d, 64);
        #pragma unroll
        for (int j = 0; j < 4; ++j) os[j] = __shfl_xor(so[j], d, 64);
        const bool hi = (lane & d) != 0;
        float Ae[4][4], Be[4][4], sa[4], sb[4];
        #pragma unroll
        for (int i = 0; i < 4; ++i)
            #pragma unroll
            for (int j = 0; j < 4; ++j) {
                Ae[i][j] = hi ? Pe[i][j] : oP[i][j];
                Be[i][j] = hi ? oP[i][j] : Pe[i][j];
            }
        #pragma unroll
        for (int j = 0; j < 4; ++j) {
            sa[j] = hi ? so[j] : os[j];
            sb[j] = hi ? os[j] : so[j];
        }
        float Ce[4][4], sc[4];
        compose4(Ae, sa, Be, sb, Ce, sc);
        #pragma unroll
        for (int i = 0; i < 4; ++i)
            #pragma unroll
            for (int j = 0; j < 4; ++j) Pe[i][j] = Ce[i][j];
        #pragma unroll
        for (int j = 0; j < 4; ++j) so[j] = sc[j];
    }

    #pragma unroll
    for (int d = 1; d < 64; d <<= 1) gold += __shfl_xor(gold, d, 64);

    if (lane == 0) {
        const float t50 = trans[30], t51 = trans[31], t52 = trans[32], t53 = trans[33];
        const float ssum = Pe[0][0] * ex2(t50 * kLog2e) + Pe[1][0] * ex2(t51 * kLog2e)
                         + Pe[2][0] * ex2(t52 * kLog2e) + Pe[3][0] * ex2(t53 * kLog2e);
        const float fwd = (so[0] + lg2(ssum)) * kLn2;
        const int lastT = tags[(size_t)b * TN + TN - 1];
        const float gfin = gold + sel4(t50, t51, t52, t53, lastT);
        out[b] = fwd - gfin;
    }
}

extern "C" void kernel_launch(void* const* d_in, const int* in_sizes, int n_in,
                              void* d_out, int out_size, void* d_ws, size_t ws_size,
                              hipStream_t stream)
{
    const float* feats = (const float*)d_in[0];
    const float* bias  = (const float*)d_in[1];
    const int*   tags  = (const int*)d_in[2];
    const float* trans = (const float*)d_in[3];
    const float* wsh   = (const float*)d_in[4];
    const float* bno   = (const float*)d_in[5];
    const float* bwi   = (const float*)d_in[6];
    const float* wwo   = (const float*)d_in[7];
    const float* wno   = (const float*)d_in[8];
    const float* mult  = (const float*)d_in[9];
    float* out = (float*)d_out;
    float* matAll = (float*)d_ws;

    const size_t need128 = (size_t)BN * 128 * SLOT * sizeof(float);  // 25.2 MB
    if (ws_size >= need128) {
        crf_phase1<128><<<(128 * BN) / 256, 256, 0, stream>>>(
            feats, bias, tags, trans, wsh, bno, bwi, wwo, wno, mult, matAll);
        crf_phase2<128><<<(BN * 64) / 256, 256, 0, stream>>>(matAll, trans, tags, out);
    } else {
        crf_phase1<64><<<(64 * BN) / 256, 256, 0, stream>>>(
            feats, bias, tags, trans, wsh, bno, bwi, wwo, wno, mult, matAll);
        crf_phase2<64><<<(BN * 64) / 256, 256, 0, stream>>>(matAll, trans, tags, out);
    }
}

// Round 6
// 221.139 us; speedup vs baseline: 2.4978x; 1.0538x over previous
//
#include <hip/hip_runtime.h>

#define BN 2048   // batch
#define TN 2048   // time
#define TRIP 4    // steps per pipelined trip
#define SLOT 24   // floats per (b,chunk) slot: 16 P + 4 off + 1 gold + 3 pad

__device__ __forceinline__ float ex2(float x){ return __builtin_amdgcn_exp2f(x); }
__device__ __forceinline__ float lg2(float x){ return __builtin_amdgcn_logf(x); }
__device__ __forceinline__ float rcpf(float x){ return __builtin_amdgcn_rcpf(x); }
__device__ __forceinline__ float rfl(float x){
    return __int_as_float(__builtin_amdgcn_readfirstlane(__float_as_int(x)));
}

constexpr float kLog2e = 1.4426950408889634f;
constexpr float kLn2   = 0.6931471805599453f;

__device__ __forceinline__ float fast_tanh(float x){
    float ax = fabsf(x);
    float e  = ex2(ax * (-2.0f * kLog2e));     // exp(-2|x|)
    float t  = (1.0f - e) * rcpf(1.0f + e);
    return copysignf(t, x);
}

__device__ __forceinline__ float sel4(float v0, float v1, float v2, float v3, int idx){
    float r = (idx == 1) ? v1 : v0;
    r = (idx == 2) ? v2 : r;
    r = (idx == 3) ? v3 : r;
    return r;
}

// Load one trip (TRIP=4 steps) of feats/bias/tags with full-line float4 loads.
// fb/bp/tp are per-lane chunk base pointers; q is the trip index.
__device__ __forceinline__ void load_trip(
    const float* __restrict__ fb, const float* __restrict__ bp,
    const int* __restrict__ tp, int q,
    float (&Fr)[TRIP * 6], float (&Bv)[TRIP], int (&Tg)[TRIP])
{
    const float4* f4 = (const float4*)(fb + q * (TRIP * 6));
    #pragma unroll
    for (int r = 0; r < TRIP * 6 / 4; ++r) {
        const float4 v = f4[r];
        Fr[4*r+0] = v.x; Fr[4*r+1] = v.y; Fr[4*r+2] = v.z; Fr[4*r+3] = v.w;
    }
    const float4 bv = *(const float4*)(bp + q * TRIP);
    Bv[0] = bv.x; Bv[1] = bv.y; Bv[2] = bv.z; Bv[3] = bv.w;
    const int4 tv = *(const int4*)(tp + q * TRIP);
    Tg[0] = tv.x; Tg[1] = tv.y; Tg[2] = tv.z; Tg[3] = tv.w;
}

// Evolve NCOL exp-space alpha columns through one chunk (TCH steps) with a
// ping-pong register pipeline: trip k+1's global loads are issued BEFORE
// trip k's compute, so the load latency overlaps compute.
template <int NCOL, bool CHUNK0, int TCH>
__device__ __forceinline__ void run_chunk(
    int b, int c,
    const float* __restrict__ feats, const float* __restrict__ bias,
    const int* __restrict__ tags,
    const float (&AL)[4][4], const float (&M)[4][4],
    const float (&wsv)[4], const float (&wwv)[4], const float (&wnv)[4],
    float bwc, float bnc, const float* sA, const float* sM,
    const float (&tc4)[4],
    float (&P)[4][NCOL], float (&lacc)[NCOL], float& gold, int& prev)
{
    constexpr int NT = TCH / TRIP;
    const float* fb = feats + ((size_t)b * TN + c * TCH) * 6;
    const float* bp = bias + (size_t)b * TN + c * TCH;
    const int*   tp = tags + (size_t)b * TN + c * TCH;

    float Fr[2][TRIP * 6];
    float Bv[2][TRIP];
    int   Tg[2][TRIP];
    load_trip(fb, bp, tp, 0, Fr[0], Bv[0], Tg[0]);

    #pragma unroll
    for (int bt = 0; bt < NT; ++bt) {
        const int cur = bt & 1, nxt = cur ^ 1;
        if (bt + 1 < NT)
            load_trip(fb, bp, tp, bt + 1, Fr[nxt], Bv[nxt], Tg[nxt]);

        #pragma unroll
        for (int s = 0; s < TRIP; ++s) {
            const float fi0 = Fr[cur][s*6+0], fi1 = Fr[cur][s*6+1];
            const float fi2 = Fr[cur][s*6+2], fi3 = Fr[cur][s*6+3];
            if (CHUNK0 && bt == 0 && s == 0) {
                // closed-form t=0: alpha1[i] = f[0,i] + trans[i,START]
                const float a0 = fi0 + tc4[0], a1 = fi1 + tc4[1];
                const float a2 = fi2 + tc4[2], a3 = fi3 + tc4[3];
                const float mx = fmaxf(fmaxf(a0, a1), fmaxf(a2, a3));
                P[0][0] = ex2((a0 - mx) * kLog2e);
                P[1][0] = ex2((a1 - mx) * kLog2e);
                P[2][0] = ex2((a2 - mx) * kLog2e);
                P[3][0] = ex2((a3 - mx) * kLog2e);
                lacc[0] = mx * kLog2e;
                const int tg0 = Tg[cur][0];
                gold = sel4(tc4[0], tc4[1], tc4[2], tc4[3], tg0)
                     + sel4(fi0, fi1, fi2, fi3, tg0);
                prev = tg0;
                continue;
            }
            const float bv = Bv[cur][s];
            const int tg = Tg[cur][s];
            const bool hw = bv > 0.5f;
            const float bc = hw ? bwc : bnc;
            float g[4], gL[4];
            #pragma unroll
            for (int j = 0; j < 4; ++j) {
                float x = fmaf(bv, wsv[j], bc);
                g[j]  = (hw ? wwv[j] : wnv[j]) * fast_tanh(x);
                gL[j] = g[j] * kLog2e;
            }
            const float fiL[4] = { fi0 * kLog2e, fi1 * kLog2e,
                                   fi2 * kLog2e, fi3 * kLog2e };
            float nP[4][NCOL];
            #pragma unroll
            for (int i = 0; i < 4; ++i)
                #pragma unroll
                for (int j = 0; j < NCOL; ++j) nP[i][j] = 0.0f;
            #pragma unroll
            for (int k = 0; k < 4; ++k) {
                float Ek[4];
                #pragma unroll
                for (int i = 0; i < 4; ++i)
                    Ek[i] = ex2(fmaf(gL[k], M[i][k], fiL[i] + AL[i][k]));
                #pragma unroll
                for (int j = 0; j < NCOL; ++j) {
                    const float pk = P[k][j];
                    #pragma unroll
                    for (int i = 0; i < 4; ++i) nP[i][j] = fmaf(Ek[i], pk, nP[i][j]);
                }
            }
            #pragma unroll
            for (int i = 0; i < 4; ++i)
                #pragma unroll
                for (int j = 0; j < NCOL; ++j) P[i][j] = nP[i][j];

            const int idx = tg * 4 + prev;
            gold += sA[idx] + sel4(g[0], g[1], g[2], g[3], prev) * sM[idx]
                  + sel4(fi0, fi1, fi2, fi3, tg);
            prev = tg;

            if (s == TRIP - 1) {     // exact pow2 renorm once per trip (4 steps)
                #pragma unroll
                for (int j = 0; j < NCOL; ++j) {
                    float m = fmaxf(fmaxf(P[0][j], P[1][j]), fmaxf(P[2][j], P[3][j]));
                    int ee = (int)((__float_as_uint(m) >> 23) & 255u) - 126;
                    float sc = __uint_as_float((unsigned)(127 - ee) << 23);
                    lacc[j] += (float)ee;
                    #pragma unroll
                    for (int i = 0; i < 4; ++i) P[i][j] *= sc;
                }
            }
        }
    }
}

template <int CCv>
__global__ void __launch_bounds__(256)
crf_phase1(const float* __restrict__ feats, const float* __restrict__ bias,
           const int* __restrict__ tags, const float* __restrict__ trans,
           const float* __restrict__ wsh, const float* __restrict__ bno,
           const float* __restrict__ bwi, const float* __restrict__ wwo,
           const float* __restrict__ wno, const float* __restrict__ mult,
           float* __restrict__ matAll)
{
    constexpr int TCHv = TN / CCv;
    const int tid = blockIdx.x * 256 + threadIdx.x;
    const int b = tid & (BN - 1);
    const int c = tid >> 11;        // uniform per block

    __shared__ float sA[16], sM[16];
    if (threadIdx.x < 16) {
        const int i = threadIdx.x >> 2, j = threadIdx.x & 3;
        sA[threadIdx.x] = trans[i * 6 + j];
        const float m0 = mult[j], m1 = mult[4 + j], m2 = mult[8 + j], m3 = mult[12 + j];
        const float mx = fmaxf(fmaxf(m0, m1), fmaxf(m2, m3));
        const float e0 = ex2((m0 - mx) * kLog2e), e1 = ex2((m1 - mx) * kLog2e);
        const float e2 = ex2((m2 - mx) * kLog2e), e3 = ex2((m3 - mx) * kLog2e);
        const float inv = rcpf(e0 + e1 + e2 + e3);
        const float ei = (i == 0) ? e0 : (i == 1) ? e1 : (i == 2) ? e2 : e3;
        sM[threadIdx.x] = (i == j) ? -1.0f : ei * inv;
    }
    __syncthreads();

    // M recomputed per-lane then pinned into SGPRs via readfirstlane (-16 VGPR).
    float AL[4][4], M[4][4];
    #pragma unroll
    for (int j = 0; j < 4; ++j) {
        const float m0 = mult[j], m1 = mult[4 + j], m2 = mult[8 + j], m3 = mult[12 + j];
        const float mx = fmaxf(fmaxf(m0, m1), fmaxf(m2, m3));
        const float e0 = ex2((m0 - mx) * kLog2e), e1 = ex2((m1 - mx) * kLog2e);
        const float e2 = ex2((m2 - mx) * kLog2e), e3 = ex2((m3 - mx) * kLog2e);
        const float inv = rcpf(e0 + e1 + e2 + e3);
        M[0][j] = (0 == j) ? -1.0f : rfl(e0 * inv);
        M[1][j] = (1 == j) ? -1.0f : rfl(e1 * inv);
        M[2][j] = (2 == j) ? -1.0f : rfl(e2 * inv);
        M[3][j] = (3 == j) ? -1.0f : rfl(e3 * inv);
    }
    #pragma unroll
    for (int i = 0; i < 4; ++i)
        #pragma unroll
        for (int j = 0; j < 4; ++j)
            AL[i][j] = trans[i * 6 + j] * kLog2e;
    float wsv[4], wwv[4], wnv[4];
    #pragma unroll
    for (int j = 0; j < 4; ++j) { wsv[j] = wsh[j]; wwv[j] = wwo[j]; wnv[j] = wno[j]; }
    const float bwc = bwi[0], bnc = bno[0];
    const float tc4[4] = { trans[4], trans[10], trans[16], trans[22] };

    float o[SLOT];
    float gold = 0.0f;
    int prev;
    if (c == 0) {
        float P[4][1], lacc[1];
        run_chunk<1, true, TCHv>(b, 0, feats, bias, tags, AL, M, wsv, wwv, wnv,
                                 bwc, bnc, sA, sM, tc4, P, lacc, gold, prev);
        #pragma unroll
        for (int i = 0; i < 4; ++i)
            #pragma unroll
            for (int j = 0; j < 4; ++j) o[i * 4 + j] = P[i][0];   // rank-1 lift
        #pragma unroll
        for (int j = 0; j < 4; ++j) o[16 + j] = lacc[0];
    } else {
        float P[4][4], lacc[4] = {0.f, 0.f, 0.f, 0.f};
        #pragma unroll
        for (int i = 0; i < 4; ++i)
            #pragma unroll
            for (int j = 0; j < 4; ++j) P[i][j] = (i == j) ? 1.0f : 0.0f;
        prev = tags[(size_t)b * TN + c * TCHv - 1];
        run_chunk<4, false, TCHv>(b, c, feats, bias, tags, AL, M, wsv, wwv, wnv,
                                  bwc, bnc, sA, sM, tc4, P, lacc, gold, prev);
        #pragma unroll
        for (int i = 0; i < 4; ++i)
            #pragma unroll
            for (int j = 0; j < 4; ++j) o[i * 4 + j] = P[i][j];
        #pragma unroll
        for (int j = 0; j < 4; ++j) o[16 + j] = lacc[j];
    }
    o[20] = gold; o[21] = 0.f; o[22] = 0.f; o[23] = 0.f;
    float4* s4 = (float4*)(matAll + ((size_t)b * CCv + c) * SLOT);
    #pragma unroll
    for (int q = 0; q < SLOT / 4; ++q)
        s4[q] = make_float4(o[4*q], o[4*q+1], o[4*q+2], o[4*q+3]);
}

// C = A∘B (A later, B earlier) in exp-space with per-column base-2 offsets.
__device__ __forceinline__ void compose4(
    const float (&Ae)[4][4], const float (&sa)[4],
    const float (&Be)[4][4], const float (&sb)[4],
    float (&Ce)[4][4], float (&sc)[4])
{
    const float maxA = fmaxf(fmaxf(sa[0], sa[1]), fmaxf(sa[2], sa[3]));
    float Ap[4][4];
    #pragma unroll
    for (int k = 0; k < 4; ++k) {
        const float wk = ex2(sa[k] - maxA);
        #pragma unroll
        for (int i = 0; i < 4; ++i) Ap[i][k] = Ae[i][k] * wk;
    }
    #pragma unroll
    for (int j = 0; j < 4; ++j) {
        float c0 = 0.f, c1 = 0.f, c2 = 0.f, c3 = 0.f;
        #pragma unroll
        for (int k = 0; k < 4; ++k) {
            const float bk = Be[k][j];
            c0 = fmaf(Ap[0][k], bk, c0);
            c1 = fmaf(Ap[1][k], bk, c1);
            c2 = fmaf(Ap[2][k], bk, c2);
            c3 = fmaf(Ap[3][k], bk, c3);
        }
        const float m = fmaxf(fmaxf(c0, c1), fmaxf(c2, c3));
        const int ee = (int)((__float_as_uint(m) >> 23) & 255u) - 126;
        const float scf = __uint_as_float((unsigned)(127 - ee) << 23);
        Ce[0][j] = c0 * scf; Ce[1][j] = c1 * scf;
        Ce[2][j] = c2 * scf; Ce[3][j] = c3 * scf;
        sc[j] = sb[j] + maxA + (float)ee;
    }
}

template <int CCv>
__global__ void __launch_bounds__(256)
crf_phase2(const float* __restrict__ matAll, const float* __restrict__ trans,
           const int* __restrict__ tags, float* __restrict__ out)
{
    constexpr int CPL = CCv / 64;   // chunks per lane
    const int gtid = blockIdx.x * 256 + threadIdx.x;
    const int b = gtid >> 6;
    const int lane = threadIdx.x & 63;

    const float4* base = (const float4*)(matAll + ((size_t)b * CCv + lane * CPL) * SLOT);
    float Pe[4][4], so[4], gold;
    {
        float A[SLOT];
        #pragma unroll
        for (int q = 0; q < SLOT / 4; ++q) {
            const float4 v = base[q];
            A[4*q] = v.x; A[4*q+1] = v.y; A[4*q+2] = v.z; A[4*q+3] = v.w;
        }
        #pragma unroll
        for (int i = 0; i < 4; ++i)
            #pragma unroll
            for (int j = 0; j < 4; ++j) Pe[i][j] = A[i * 4 + j];
        #pragma unroll
        for (int j = 0; j < 4; ++j) so[j] = A[16 + j];
        gold = A[20];
    }
    #pragma unroll
    for (int q = 1; q < CPL; ++q) {
        float A[SLOT];
        #pragma unroll
        for (int r = 0; r < SLOT / 4; ++r) {
            const float4 v = base[q * (SLOT / 4) + r];
            A[4*r] = v.x; A[4*r+1] = v.y; A[4*r+2] = v.z; A[4*r+3] = v.w;
        }
        float Ae[4][4], sa[4];
        #pragma unroll
        for (int i = 0; i < 4; ++i)
            #pragma unroll
            for (int j = 0; j < 4; ++j) Ae[i][j] = A[i * 4 + j];
        #pragma unroll
        for (int j = 0; j < 4; ++j) sa[j] = A[16 + j];
        gold += A[20];
        float Ce[4][4], sc[4];
        compose4(Ae, sa, Pe, so, Ce, sc);     // newer slot is the later operator
        #pragma unroll
        for (int i = 0; i < 4; ++i)
            #pragma unroll
            for (int j = 0; j < 4; ++j) Pe[i][j] = Ce[i][j];
        #pragma unroll
        for (int j = 0; j < 4; ++j) so[j] = sc[j];
    }

    #pragma unroll
    for (int d = 1; d < 64; d <<= 1) {
        float oP[4][4], os[4];
        #pragma unroll
        for (int i = 0; i < 4; ++i)
            #pragma unroll
            for (int j = 0; j < 4; ++j) oP[i][j] = __shfl_xor(Pe[i][j], d, 64);
        #pragma unroll
        for (int j = 0; j < 4; ++j) os[j] = __shfl_xor(so[j], d, 64);
        const bool hi = (lane & d) != 0;
        float Ae[4][4], Be[4][4], sa[4], sb[4];
        #pragma unroll
        for (int i = 0; i < 4; ++i)
            #pragma unroll
            for (int j = 0; j < 4; ++j) {
                Ae[i][j] = hi ? Pe[i][j] : oP[i][j];
                Be[i][j] = hi ? oP[i][j] : Pe[i][j];
            }
        #pragma unroll
        for (int j = 0; j < 4; ++j) {
            sa[j] = hi ? so[j] : os[j];
            sb[j] = hi ? os[j] : so[j];
        }
        float Ce[4][4], sc[4];
        compose4(Ae, sa, Be, sb, Ce, sc);
        #pragma unroll
        for (int i = 0; i < 4; ++i)
            #pragma unroll
            for (int j = 0; j < 4; ++j) Pe[i][j] = Ce[i][j];
        #pragma unroll
        for (int j = 0; j < 4; ++j) so[j] = sc[j];
    }

    #pragma unroll
    for (int d = 1; d < 64; d <<= 1) gold += __shfl_xor(gold, d, 64);

    if (lane == 0) {
        const float t50 = trans[30], t51 = trans[31], t52 = trans[32], t53 = trans[33];
        const float ssum = Pe[0][0] * ex2(t50 * kLog2e) + Pe[1][0] * ex2(t51 * kLog2e)
                         + Pe[2][0] * ex2(t52 * kLog2e) + Pe[3][0] * ex2(t53 * kLog2e);
        const float fwd = (so[0] + lg2(ssum)) * kLn2;
        const int lastT = tags[(size_t)b * TN + TN - 1];
        const float gfin = gold + sel4(t50, t51, t52, t53, lastT);
        out[b] = fwd - gfin;
    }
}

extern "C" void kernel_launch(void* const* d_in, const int* in_sizes, int n_in,
                              void* d_out, int out_size, void* d_ws, size_t ws_size,
                              hipStream_t stream)
{
    const float* feats = (const float*)d_in[0];
    const float* bias  = (const float*)d_in[1];
    const int*   tags  = (const int*)d_in[2];
    const float* trans = (const float*)d_in[3];
    const float* wsh   = (const float*)d_in[4];
    const float* bno   = (const float*)d_in[5];
    const float* bwi   = (const float*)d_in[6];
    const float* wwo   = (const float*)d_in[7];
    const float* wno   = (const float*)d_in[8];
    const float* mult  = (const float*)d_in[9];
    float* out = (float*)d_out;
    float* matAll = (float*)d_ws;

    const size_t need128 = (size_t)BN * 128 * SLOT * sizeof(float);  // 25.2 MB
    if (ws_size >= need128) {
        crf_phase1<128><<<(128 * BN) / 256, 256, 0, stream>>>(
            feats, bias, tags, trans, wsh, bno, bwi, wwo, wno, mult, matAll);
        crf_phase2<128><<<(BN * 64) / 256, 256, 0, stream>>>(matAll, trans, tags, out);
    } else {
        crf_phase1<64><<<(64 * BN) / 256, 256, 0, stream>>>(
            feats, bias, tags, trans, wsh, bno, bwi, wwo, wno, mult, matAll);
        crf_phase2<64><<<(BN * 64) / 256, 256, 0, stream>>>(matAll, trans, tags, out);
    }
}